// Round 5
// baseline (590.589 us; speedup 1.0000x reference)
//
#include <hip/hip_runtime.h>
#include <stdint.h>

#define HH 64
#define WW 64
#define AA 9
#define N_PER (HH*WW*AA)   // 36864
#define NB 4
#define PRE_NMS 6000
#define POST_NMS 300
#define JWORDS 94          // ceil(6000/64)
#define JROW_B 752         // bytes per mask row = 47 lanes * 16 B
#define NMS_THRESH 0.7f
#define FEAT_STRIDE 16
#define SLOTS 8

// =====================================================================
// Kernel 1: exact top-6000 select (radix on unique 64-bit composite keys)
// + LDS bitonic sort + box decode of the selected 6000. One WG per image.
// (unchanged from round 4)
// =====================================================================
__global__ void __launch_bounds__(1024) select_sort(const float* __restrict__ scores,
                                                    const float* __restrict__ deltas,
                                                    const float* __restrict__ img_info,
                                                    const float* __restrict__ anchors,
                                                    float* __restrict__ topb) // NB*PRE_NMS*4
{
#pragma clang fp contract(off)
    int b = blockIdx.x;
    int t = threadIdx.x;
    __shared__ uint32_t H[2048];
    __shared__ uint32_t S[2048];
    __shared__ uint64_t coll[1024];
    __shared__ uint64_t sortbuf[8192];
    __shared__ uint32_t ccnt, gcnt;
    __shared__ int shB1, shB2;
    __shared__ uint64_t shKstar;

    auto keyof = [&](int j) -> uint64_t {
        int a = j >> 12, hw = j & 4095;
        float sc = scores[((size_t)b*18 + 9 + a)*4096 + hw];
        uint32_t u = __float_as_uint(sc);
        u = (u & 0x80000000u) ? ~u : (u | 0x80000000u);
        uint32_t i = (uint32_t)(hw*9 + a);            // reference flat index
        return ((uint64_t)u << 32) | (uint32_t)(~i);
    };

    // ---------- pass 1: histogram of top 11 bits ----------
    H[t] = 0; H[t+1024] = 0;
    __syncthreads();
    for (int j = t; j < N_PER; j += 1024)
        atomicAdd(&H[(uint32_t)(keyof(j) >> 53)], 1u);
    __syncthreads();
    S[t] = H[t]; S[t+1024] = H[t+1024];
    __syncthreads();
    for (int off = 1; off < 2048; off <<= 1) {
        uint32_t v0 = S[t]      + ((t+off)      < 2048 ? S[t+off]      : 0);
        uint32_t v1 = S[t+1024] + ((t+1024+off) < 2048 ? S[t+1024+off] : 0);
        __syncthreads();
        S[t] = v0; S[t+1024] = v1;
        __syncthreads();
    }
    for (int k = 0; k < 2; ++k) {
        int bin = t + k*1024;
        uint32_t above = (bin < 2047) ? S[bin+1] : 0;
        if (S[bin] >= PRE_NMS && above < PRE_NMS) shB1 = bin;
    }
    __syncthreads();
    int B1 = shB1;
    uint32_t C1 = (B1 < 2047) ? S[B1+1] : 0;
    uint32_t R1 = PRE_NMS - C1;
    __syncthreads();

    // ---------- pass 2: histogram of next 11 bits within bin B1 ----------
    H[t] = 0; H[t+1024] = 0;
    __syncthreads();
    for (int j = t; j < N_PER; j += 1024) {
        uint64_t k64 = keyof(j);
        if ((int)(k64 >> 53) == B1)
            atomicAdd(&H[(uint32_t)((k64 >> 42) & 2047)], 1u);
    }
    __syncthreads();
    S[t] = H[t]; S[t+1024] = H[t+1024];
    __syncthreads();
    for (int off = 1; off < 2048; off <<= 1) {
        uint32_t v0 = S[t]      + ((t+off)      < 2048 ? S[t+off]      : 0);
        uint32_t v1 = S[t+1024] + ((t+1024+off) < 2048 ? S[t+1024+off] : 0);
        __syncthreads();
        S[t] = v0; S[t+1024] = v1;
        __syncthreads();
    }
    for (int k = 0; k < 2; ++k) {
        int bin = t + k*1024;
        uint32_t above = (bin < 2047) ? S[bin+1] : 0;
        if (S[bin] >= R1 && above < R1) shB2 = bin;
    }
    if (t == 0) ccnt = 0;
    __syncthreads();
    int B2 = shB2;
    uint32_t C2r = (B2 < 2047) ? S[B2+1] : 0;
    uint32_t R2 = R1 - C2r;
    uint64_t prefix = (((uint64_t)B1) << 11) | (uint64_t)B2;

    // ---------- pass 3: collect sub-bin keys, find exact K* ----------
    for (int j = t; j < N_PER; j += 1024) {
        uint64_t k64 = keyof(j);
        if ((k64 >> 42) == prefix) {
            uint32_t p = atomicAdd(&ccnt, 1u);
            if (p < 1024) coll[p] = k64;
        }
    }
    __syncthreads();
    int m = (int)min(ccnt, 1024u);
    for (int idx = t; idx < m; idx += 1024) {
        uint64_t k64 = coll[idx];
        uint32_t r = 0;
        for (int q = 0; q < m; ++q) r += (coll[q] > k64) ? 1u : 0u;
        if (r == R2 - 1) shKstar = k64;
    }
    if (t == 0) gcnt = 0;
    __syncthreads();
    uint64_t Kstar = shKstar;

    // ---------- gather selected keys (key >= K*) into sortbuf ----------
    for (int s = t; s < 8192; s += 1024) sortbuf[s] = 0ull;
    __syncthreads();
    for (int j = t; j < N_PER; j += 1024) {
        uint64_t k64 = keyof(j);
        if (k64 >= Kstar) {
            uint32_t p = atomicAdd(&gcnt, 1u);
            sortbuf[p] = k64;
        }
    }
    __syncthreads();

    // ---------- bitonic sort 8192 u64 descending, all in LDS ----------
    for (int size = 2; size <= 8192; size <<= 1) {
        for (int stride = size >> 1; stride > 0; stride >>= 1) {
            #pragma unroll
            for (int k = 0; k < 4; ++k) {
                int p = t + (k << 10);
                int idx = ((p & ~(stride-1)) << 1) | (p & (stride-1));
                int q = idx | stride;
                bool up = (idx & size) == 0;
                uint64_t x = sortbuf[idx], y = sortbuf[q];
                if (up ? (x < y) : (x > y)) { sortbuf[idx] = y; sortbuf[q] = x; }
            }
            __syncthreads();
        }
    }

    // ---------- decode boxes for the sorted top-6000 ----------
    float maxx = img_info[1] - 1.0f;
    float maxy = img_info[0] - 1.0f;
    for (int r = t; r < PRE_NMS; r += 1024) {
        uint64_t k64 = sortbuf[r];
        uint32_t i = ~(uint32_t)(k64 & 0xFFFFFFFFu);
        int a = (int)(i % 9u);
        int hw = (int)(i / 9u);
        int h = hw >> 6, w = hw & 63;
        float sx = (float)(w * FEAT_STRIDE);
        float sy = (float)(h * FEAT_STRIDE);
        float ax1 = anchors[a*4+0] + sx;
        float ay1 = anchors[a*4+1] + sy;
        float ax2 = anchors[a*4+2] + sx;
        float ay2 = anchors[a*4+3] + sy;
        float width  = ax2 - ax1 + 1.0f;
        float height = ay2 - ay1 + 1.0f;
        float cx = ax1 + 0.5f * width;
        float cy = ay1 + 0.5f * height;
        size_t base = ((size_t)b*36 + a*4) * 4096 + hw;
        float dx = deltas[base];
        float dy = deltas[base + 4096];
        float dw = deltas[base + 2*4096];
        float dh = deltas[base + 3*4096];
        float pcx = dx * width + cx;
        float pcy = dy * height + cy;
        float pw = (float)exp((double)dw) * width;     // correctly-rounded f32 exp
        float ph = (float)exp((double)dh) * height;
        float x1 = pcx - 0.5f * pw;
        float y1 = pcy - 0.5f * ph;
        float x2 = pcx + 0.5f * pw;
        float y2 = pcy + 0.5f * ph;
        x1 = fminf(fmaxf(x1, 0.0f), maxx);
        y1 = fminf(fmaxf(y1, 0.0f), maxy);
        x2 = fminf(fmaxf(x2, 0.0f), maxx);
        y2 = fminf(fmaxf(y2, 0.0f), maxy);
        *(float4*)(topb + ((size_t)b*PRE_NMS + r)*4) = make_float4(x1, y1, x2, y2);
    }
}

// =====================================================================
// Kernel 2: triangular suppression bitmask (unchanged from round 4).
// =====================================================================
__global__ void __launch_bounds__(64) nms_mask(const float* __restrict__ topb,
                                               uint64_t* __restrict__ mask) {
#pragma clang fp contract(off)
    int jblock = blockIdx.x;
    int iblock = blockIdx.y;
    if (jblock < iblock) return;
    int b = blockIdx.z;
    int t = threadIdx.x;
    __shared__ float4 jb[64];
    __shared__ float jarea[64];
    int j0 = jblock*64;
    int jcount = min(64, PRE_NMS - j0);
    if (t < jcount) {
        float4 bj = *(const float4*)(topb + ((size_t)b*PRE_NMS + j0 + t)*4);
        jb[t] = bj;
        jarea[t] = (bj.z - bj.x + 1.0f) * (bj.w - bj.y + 1.0f);
    }
    __syncthreads();
    int i = iblock*64 + t;
    if (i >= PRE_NMS) return;
    float4 bi = *(const float4*)(topb + ((size_t)b*PRE_NMS + i)*4);
    float areai = (bi.z - bi.x + 1.0f) * (bi.w - bi.y + 1.0f);
    uint64_t bits = 0;
    for (int jj = 0; jj < jcount; ++jj) {
        float4 bj = jb[jj];
        float xx1 = fmaxf(bi.x, bj.x);
        float yy1 = fmaxf(bi.y, bj.y);
        float xx2 = fminf(bi.z, bj.z);
        float yy2 = fminf(bi.w, bj.w);
        float iw = fmaxf(0.0f, xx2 - xx1 + 1.0f);
        float ih = fmaxf(0.0f, yy2 - yy1 + 1.0f);
        float inter = iw * ih;
        float iou = inter / ((areai + jarea[jj]) - inter);
        if (iou > NMS_THRESH) bits |= (1ull << jj);
    }
    mask[((size_t)b*PRE_NMS + i)*JWORDS + jblock] = bits;
}

// =====================================================================
// Kernel 3: single-wave greedy scan with LDS ring + counted vmcnt.
// 8-slot LDS ring fed by global_load_lds (no dest regs for compiler to
// track). Wave-uniform queue of issued rows (packed u64 bitfields, no
// scratch). Predictions are monotone (suppression only removes), so the
// actual next keep always appears in the queue in issue order; stale
// entries before it are discarded under the same counted wait.
// =====================================================================
__global__ void __launch_bounds__(64) nms_scan_ring(const uint64_t* __restrict__ mask,
                                                    const float* __restrict__ topb,
                                                    float* __restrict__ out) {
    int b = blockIdx.x;
    int l = threadIdx.x;
    __shared__ __align__(16) uint8_t rows[SLOTS][1024];
    __shared__ int keepL[POST_NMS];

    const uint8_t* mrow0 = (const uint8_t*)mask + (size_t)b * PRE_NMS * JROW_B;
    int lane16 = l * 16;

    uint64_t r0, r1;                       // remv words 2l, 2l+1
    if (l < 46)      { r0 = 0ull; r1 = 0ull; }
    else if (l == 46){ r0 = 0ull; r1 = ~((1ull << 48) - 1); } // ranks 6000..6015 dead
    else             { r0 = ~0ull; r1 = ~0ull; }              // lanes 47..63 own nothing

    // ---- packed wave-uniform queue: 16-bit tags, 4-bit slots ----
    uint64_t qt01 = 0, qt45 = 0;           // tags entries 0..3 / 4..7
    uint32_t qsl = 0;                      // slots, 4b each
    uint32_t freem = (1u << SLOTS) - 1;
    int qn = 0;

    auto qtag_at  = [&](int i) -> int {
        uint64_t w = (i < 4) ? qt01 : qt45;
        return (int)((w >> ((i & 3) * 16)) & 0xFFFFull);
    };
    auto qslot_at = [&](int i) -> int { return (int)((qsl >> (i * 4)) & 0xFu); };
    auto qshift = [&](int cnt) {           // drop cnt front entries
        int s = cnt * 16;
        if (cnt >= 8)      { qt01 = 0; qt45 = 0; }
        else if (cnt > 4)  { qt01 = qt45 >> (s - 64); qt45 = 0; }
        else if (cnt == 4) { qt01 = qt45; qt45 = 0; }
        else if (cnt > 0)  { qt01 = (qt01 >> s) | (qt45 << (64 - s)); qt45 >>= s; }
        qsl = (cnt >= 8) ? 0u : (qsl >> (cnt * 4));
        qn -= cnt;
    };
    auto issue = [&](int r) {
        int s = (int)__builtin_ctz(freem);
        freem &= ~(1u << s);
        const uint8_t* src = mrow0 + (size_t)r * JROW_B + lane16;
        __builtin_amdgcn_global_load_lds(
            (const __attribute__((address_space(1))) uint32_t*)src,
            (__attribute__((address_space(3))) uint32_t*)&rows[s][0],
            16, 0, 0);
        if (qn < 4) qt01 |= ((uint64_t)(uint32_t)r) << (qn * 16);
        else        qt45 |= ((uint64_t)(uint32_t)r) << ((qn - 4) * 16);
        qsl |= ((uint32_t)s) << (qn * 4);
        qn++;
    };
    auto vwait = [&](int n) {
        switch (n) {
            case 0: asm volatile("s_waitcnt vmcnt(0)" ::: "memory"); break;
            case 1: asm volatile("s_waitcnt vmcnt(1)" ::: "memory"); break;
            case 2: asm volatile("s_waitcnt vmcnt(2)" ::: "memory"); break;
            case 3: asm volatile("s_waitcnt vmcnt(3)" ::: "memory"); break;
            case 4: asm volatile("s_waitcnt vmcnt(4)" ::: "memory"); break;
            case 5: asm volatile("s_waitcnt vmcnt(5)" ::: "memory"); break;
            case 6: asm volatile("s_waitcnt vmcnt(6)" ::: "memory"); break;
            default: asm volatile("s_waitcnt vmcnt(7)" ::: "memory"); break;
        }
        __builtin_amdgcn_sched_barrier(0);
    };

    auto firstlive = [&](uint64_t a0, uint64_t a1) -> int {
        int local = a0 ? (l*128 + __builtin_ctzll(a0))
                       : (a1 ? (l*128 + 64 + __builtin_ctzll(a1)) : 0x7FFFFFFF);
        uint64_t mb = __ballot((a0 | a1) != 0ull);
        if (mb == 0ull) return -1;
        int fl = __builtin_ctzll(mb);
        return __builtin_amdgcn_readlane(local, fl);
    };
    auto clearbit = [&](uint64_t& c0, uint64_t& c1, int n) {
        if (l == (n >> 7)) {
            if (n & 64) c1 &= ~(1ull << (n & 63));
            else        c0 &= ~(1ull << (n & 63));
        }
    };

    int cur = 0, nkeep = 0;
    // prologue: before any suppression the first predicted keeps are 0,1,2,3
    issue(0); issue(1); issue(2); issue(3);

    while (true) {
        if (l == 0) keepL[nkeep] = cur;
        nkeep++;
        if (nkeep >= POST_NMS) break;

        // locate cur in the queue (monotone predictions => present unless horizon starved)
        int k = -1;
        for (int i = 0; i < qn; ++i)
            if (qtag_at(i) == cur) { k = i; break; }
        if (k < 0) {                       // rare: drain + fresh load
            asm volatile("s_waitcnt vmcnt(0)" ::: "memory");
            __builtin_amdgcn_sched_barrier(0);
            freem = (1u << SLOTS) - 1; qt01 = 0; qt45 = 0; qsl = 0; qn = 0;
            issue(cur);
            asm volatile("s_waitcnt vmcnt(0)" ::: "memory");
            __builtin_amdgcn_sched_barrier(0);
            k = 0;
        } else {
            vwait(qn - k - 1);             // counted wait: entries 0..k complete
        }
        int slot = qslot_at(k);
        for (int i = 0; i <= k; ++i) freem |= (1u << qslot_at(i));
        qshift(k + 1);

        // consume row from LDS (after the counted wait + sched_barrier)
        uint64_t w0 = 0, w1 = 0;
        if (l < 47) {
            const uint64_t* rp = (const uint64_t*)&rows[slot][lane16];
            w0 = rp[0]; w1 = rp[1];
        }
        r0 |= w0; r1 |= w1;                // diagonal self-bit is in the row

        uint64_t lv0 = ~r0, lv1 = ~r1;
        int n1 = firstlive(lv0, lv1);      // EXACT next keep
        if (n1 < 0) break;
        uint64_t c0 = lv0, c1 = lv1;
        clearbit(c0, c1, n1);
        int n2 = firstlive(c0, c1);
        int n3 = -1, n4 = -1;
        if (n2 >= 0) {
            clearbit(c0, c1, n2);
            n3 = firstlive(c0, c1);
            if (n3 >= 0) { clearbit(c0, c1, n3); n4 = firstlive(c0, c1); }
        }

        // top-up: ensure loads for n1..n4 are in flight (subsequence match)
        int qi = 0;
        auto topup = [&](int p) -> bool {
            if (p < 0) return false;
            for (int i = qi; i < qn; ++i)
                if (qtag_at(i) == p) { qi = i + 1; return true; }
            if (qn >= SLOTS) return false;
            issue(p); qi = qn;
            return true;
        };
        bool ok = topup(n1) && topup(n2) && topup(n3) && topup(n4);
        (void)ok;

        cur = n1;
    }
    __syncthreads();

    for (int k2 = l; k2 < POST_NMS; k2 += 64) {
        float* o = out + ((size_t)b*POST_NMS + k2)*5;
        o[0] = (float)b;
        if (k2 < nkeep) {
            float4 bx = *(const float4*)(topb + ((size_t)b*PRE_NMS + keepL[k2])*4);
            o[1] = bx.x; o[2] = bx.y; o[3] = bx.z; o[4] = bx.w;
        } else {
            o[1] = 0.0f; o[2] = 0.0f; o[3] = 0.0f; o[4] = 0.0f;
        }
    }
}

extern "C" void kernel_launch(void* const* d_in, const int* in_sizes, int n_in,
                              void* d_out, int out_size, void* d_ws, size_t ws_size,
                              hipStream_t stream) {
    const float* scores   = (const float*)d_in[0];
    const float* deltas   = (const float*)d_in[1];
    const float* img_info = (const float*)d_in[2];
    const float* anchors  = (const float*)d_in[3];
    float* out = (float*)d_out;

    uint8_t* ws = (uint8_t*)d_ws;
    float*    topb = (float*)ws;                    //   384,000 B (+pad)
    uint64_t* mask = (uint64_t*)(ws + 393216);      // 18,048,000 B + 4 KB pad for lane 47..63 overreach

    select_sort<<<NB, 1024, 0, stream>>>(scores, deltas, img_info, anchors, topb);

    dim3 mg(JWORDS, JWORDS, NB);
    nms_mask<<<mg, 64, 0, stream>>>(topb, mask);

    nms_scan_ring<<<NB, 64, 0, stream>>>(mask, topb, out);
}

// Round 6
// 242.662 us; speedup vs baseline: 2.4338x; 2.4338x over previous
//
#include <hip/hip_runtime.h>
#include <stdint.h>

#define HH 64
#define WW 64
#define AA 9
#define N_PER (HH*WW*AA)   // 36864
#define NB 4
#define PRE_NMS 6000
#define POST_NMS 300
#define NMS_THRESH 0.7f
#define FEAT_STRIDE 16
#define M 1024             // in-LDS NMS candidate window
#define MW 16              // u64 words per mask row (1024/64)

// =====================================================================
// Kernel 1: exact top-6000 select (radix on unique 64-bit composite keys)
// + LDS bitonic sort + box decode of the selected 6000. One WG per image.
// (unchanged from rounds 4/5 — known correct; this round finally exposes
// its duration in the profile)
// =====================================================================
__global__ void __launch_bounds__(1024) select_sort(const float* __restrict__ scores,
                                                    const float* __restrict__ deltas,
                                                    const float* __restrict__ img_info,
                                                    const float* __restrict__ anchors,
                                                    float* __restrict__ topb) // NB*PRE_NMS*4
{
#pragma clang fp contract(off)
    int b = blockIdx.x;
    int t = threadIdx.x;
    __shared__ uint32_t H[2048];
    __shared__ uint32_t S[2048];
    __shared__ uint64_t coll[1024];
    __shared__ uint64_t sortbuf[8192];
    __shared__ uint32_t ccnt, gcnt;
    __shared__ int shB1, shB2;
    __shared__ uint64_t shKstar;

    auto keyof = [&](int j) -> uint64_t {
        int a = j >> 12, hw = j & 4095;
        float sc = scores[((size_t)b*18 + 9 + a)*4096 + hw];
        uint32_t u = __float_as_uint(sc);
        u = (u & 0x80000000u) ? ~u : (u | 0x80000000u);
        uint32_t i = (uint32_t)(hw*9 + a);            // reference flat index
        return ((uint64_t)u << 32) | (uint32_t)(~i);
    };

    // ---------- pass 1: histogram of top 11 bits ----------
    H[t] = 0; H[t+1024] = 0;
    __syncthreads();
    for (int j = t; j < N_PER; j += 1024)
        atomicAdd(&H[(uint32_t)(keyof(j) >> 53)], 1u);
    __syncthreads();
    S[t] = H[t]; S[t+1024] = H[t+1024];
    __syncthreads();
    for (int off = 1; off < 2048; off <<= 1) {
        uint32_t v0 = S[t]      + ((t+off)      < 2048 ? S[t+off]      : 0);
        uint32_t v1 = S[t+1024] + ((t+1024+off) < 2048 ? S[t+1024+off] : 0);
        __syncthreads();
        S[t] = v0; S[t+1024] = v1;
        __syncthreads();
    }
    for (int k = 0; k < 2; ++k) {
        int bin = t + k*1024;
        uint32_t above = (bin < 2047) ? S[bin+1] : 0;
        if (S[bin] >= PRE_NMS && above < PRE_NMS) shB1 = bin;
    }
    __syncthreads();
    int B1 = shB1;
    uint32_t C1 = (B1 < 2047) ? S[B1+1] : 0;
    uint32_t R1 = PRE_NMS - C1;
    __syncthreads();

    // ---------- pass 2: histogram of next 11 bits within bin B1 ----------
    H[t] = 0; H[t+1024] = 0;
    __syncthreads();
    for (int j = t; j < N_PER; j += 1024) {
        uint64_t k64 = keyof(j);
        if ((int)(k64 >> 53) == B1)
            atomicAdd(&H[(uint32_t)((k64 >> 42) & 2047)], 1u);
    }
    __syncthreads();
    S[t] = H[t]; S[t+1024] = H[t+1024];
    __syncthreads();
    for (int off = 1; off < 2048; off <<= 1) {
        uint32_t v0 = S[t]      + ((t+off)      < 2048 ? S[t+off]      : 0);
        uint32_t v1 = S[t+1024] + ((t+1024+off) < 2048 ? S[t+1024+off] : 0);
        __syncthreads();
        S[t] = v0; S[t+1024] = v1;
        __syncthreads();
    }
    for (int k = 0; k < 2; ++k) {
        int bin = t + k*1024;
        uint32_t above = (bin < 2047) ? S[bin+1] : 0;
        if (S[bin] >= R1 && above < R1) shB2 = bin;
    }
    if (t == 0) ccnt = 0;
    __syncthreads();
    int B2 = shB2;
    uint32_t C2r = (B2 < 2047) ? S[B2+1] : 0;
    uint32_t R2 = R1 - C2r;
    uint64_t prefix = (((uint64_t)B1) << 11) | (uint64_t)B2;

    // ---------- pass 3: collect sub-bin keys, find exact K* ----------
    for (int j = t; j < N_PER; j += 1024) {
        uint64_t k64 = keyof(j);
        if ((k64 >> 42) == prefix) {
            uint32_t p = atomicAdd(&ccnt, 1u);
            if (p < 1024) coll[p] = k64;
        }
    }
    __syncthreads();
    int m = (int)min(ccnt, 1024u);
    for (int idx = t; idx < m; idx += 1024) {
        uint64_t k64 = coll[idx];
        uint32_t r = 0;
        for (int q = 0; q < m; ++q) r += (coll[q] > k64) ? 1u : 0u;
        if (r == R2 - 1) shKstar = k64;
    }
    if (t == 0) gcnt = 0;
    __syncthreads();
    uint64_t Kstar = shKstar;

    // ---------- gather selected keys (key >= K*) into sortbuf ----------
    for (int s = t; s < 8192; s += 1024) sortbuf[s] = 0ull;
    __syncthreads();
    for (int j = t; j < N_PER; j += 1024) {
        uint64_t k64 = keyof(j);
        if (k64 >= Kstar) {
            uint32_t p = atomicAdd(&gcnt, 1u);
            sortbuf[p] = k64;
        }
    }
    __syncthreads();

    // ---------- bitonic sort 8192 u64 descending, all in LDS ----------
    for (int size = 2; size <= 8192; size <<= 1) {
        for (int stride = size >> 1; stride > 0; stride >>= 1) {
            #pragma unroll
            for (int k = 0; k < 4; ++k) {
                int p = t + (k << 10);
                int idx = ((p & ~(stride-1)) << 1) | (p & (stride-1));
                int q = idx | stride;
                bool up = (idx & size) == 0;
                uint64_t x = sortbuf[idx], y = sortbuf[q];
                if (up ? (x < y) : (x > y)) { sortbuf[idx] = y; sortbuf[q] = x; }
            }
            __syncthreads();
        }
    }

    // ---------- decode boxes for the sorted top-6000 ----------
    float maxx = img_info[1] - 1.0f;
    float maxy = img_info[0] - 1.0f;
    for (int r = t; r < PRE_NMS; r += 1024) {
        uint64_t k64 = sortbuf[r];
        uint32_t i = ~(uint32_t)(k64 & 0xFFFFFFFFu);
        int a = (int)(i % 9u);
        int hw = (int)(i / 9u);
        int h = hw >> 6, w = hw & 63;
        float sx = (float)(w * FEAT_STRIDE);
        float sy = (float)(h * FEAT_STRIDE);
        float ax1 = anchors[a*4+0] + sx;
        float ay1 = anchors[a*4+1] + sy;
        float ax2 = anchors[a*4+2] + sx;
        float ay2 = anchors[a*4+3] + sy;
        float width  = ax2 - ax1 + 1.0f;
        float height = ay2 - ay1 + 1.0f;
        float cx = ax1 + 0.5f * width;
        float cy = ay1 + 0.5f * height;
        size_t base = ((size_t)b*36 + a*4) * 4096 + hw;
        float dx = deltas[base];
        float dy = deltas[base + 4096];
        float dw = deltas[base + 2*4096];
        float dh = deltas[base + 3*4096];
        float pcx = dx * width + cx;
        float pcy = dy * height + cy;
        float pw = (float)exp((double)dw) * width;     // correctly-rounded f32 exp
        float ph = (float)exp((double)dh) * height;
        float x1 = pcx - 0.5f * pw;
        float y1 = pcy - 0.5f * ph;
        float x2 = pcx + 0.5f * pw;
        float y2 = pcy + 0.5f * ph;
        x1 = fminf(fmaxf(x1, 0.0f), maxx);
        y1 = fminf(fmaxf(y1, 0.0f), maxy);
        x2 = fminf(fmaxf(x2, 0.0f), maxx);
        y2 = fminf(fmaxf(y2, 0.0f), maxy);
        *(float4*)(topb + ((size_t)b*PRE_NMS + r)*4) = make_float4(x1, y1, x2, y2);
    }
}

// =====================================================================
// Kernel 2: suppression bitmask for the TOP-1024 window only.
// msk[b][i][w] (w<16): bit j-64w set iff IoU(rank i, rank j) > 0.7.
// Full square (self-bit included; bits j<i harmless to the walk).
// Grid-parallel: 16x16x4 blocks of 64 threads, 1M IoUs total.
// =====================================================================
__global__ void __launch_bounds__(64) nms_mask_small(const float* __restrict__ topb,
                                                     uint64_t* __restrict__ msk) {
#pragma clang fp contract(off)
    int jblock = blockIdx.x;  // 0..15
    int iblock = blockIdx.y;  // 0..15
    int b = blockIdx.z;
    int t = threadIdx.x;      // 0..63
    __shared__ float4 jb[64];
    __shared__ float jarea[64];
    int j0 = jblock*64;
    {
        float4 bj = *(const float4*)(topb + ((size_t)b*PRE_NMS + j0 + t)*4);
        jb[t] = bj;
        jarea[t] = (bj.z - bj.x + 1.0f) * (bj.w - bj.y + 1.0f);
    }
    __syncthreads();
    int i = iblock*64 + t;
    float4 bi = *(const float4*)(topb + ((size_t)b*PRE_NMS + i)*4);
    float areai = (bi.z - bi.x + 1.0f) * (bi.w - bi.y + 1.0f);
    uint64_t bits = 0;
    for (int jj = 0; jj < 64; ++jj) {
        float4 bj = jb[jj];
        float xx1 = fmaxf(bi.x, bj.x);
        float yy1 = fmaxf(bi.y, bj.y);
        float xx2 = fminf(bi.z, bj.z);
        float yy2 = fminf(bi.w, bj.w);
        float iw = fmaxf(0.0f, xx2 - xx1 + 1.0f);
        float ih = fmaxf(0.0f, yy2 - yy1 + 1.0f);
        float inter = iw * ih;
        float iou = inter / ((areai + jarea[jj]) - inter);
        if (iou > NMS_THRESH) bits |= (1ull << jj);
    }
    msk[((size_t)b*M + i)*MW + jblock] = bits;
}

// =====================================================================
// Kernel 3: single-wave greedy scan, mask fully in LDS (128 KB).
// Per keep: one conflict-free ds_read_b64 (lanes 0..15 -> 32 banks) +
// OR + ballot/readlane. No barriers, no global traffic in the loop.
// Fallback (exact, rarely taken): lazy lane-parallel NMS over ranks
// >= 1024 in 64-wide batches vs the kept list in LDS.
// =====================================================================
__global__ void __launch_bounds__(64) nms_scan_lds(const uint64_t* __restrict__ msk,
                                                   const float* __restrict__ topb,
                                                   float* __restrict__ out) {
#pragma clang fp contract(off)
    int b = blockIdx.x;
    int l = threadIdx.x;
    __shared__ __align__(16) uint64_t rows[M][MW];   // 131,072 B
    __shared__ int keepL[POST_NMS];
    __shared__ float skx1[POST_NMS], sky1[POST_NMS], skx2[POST_NMS], sky2[POST_NMS], skar[POST_NMS];

    // ---- stage the 128 KB mask into LDS (linear, wave-uniform dest) ----
    const uint8_t* src0 = (const uint8_t*)(msk + (size_t)b*M*MW);
    uint8_t* dst0 = (uint8_t*)&rows[0][0];
    for (int it = 0; it < (M*MW*8)/1024; ++it) {     // 128 issues of 1 KB
        __builtin_amdgcn_global_load_lds(
            (const __attribute__((address_space(1))) uint32_t*)(src0 + it*1024 + l*16),
            (__attribute__((address_space(3))) uint32_t*)(dst0 + it*1024 + l*16),
            16, 0, 0);
    }
    asm volatile("s_waitcnt vmcnt(0)" ::: "memory");
    __builtin_amdgcn_sched_barrier(0);

    // ---- phase A: in-LDS bit walk over ranks 0..1023 ----
    uint64_t remv = 0ull;      // lane l<16 owns bits [64l, 64l+64)
    int nkeep = 0;
    int cur = 0;               // rank 0 always kept first
    bool exhausted = false;
    while (true) {
        if (l == 0) keepL[nkeep] = cur;
        nkeep++;
        if (nkeep >= POST_NMS) break;
        uint64_t rw = (l < MW) ? rows[cur][l] : 0ull;
        remv |= rw;            // row includes self-bit (IoU=1)
        uint64_t live = (l < MW) ? ~remv : 0ull;
        int local = live ? (l*64 + (int)__builtin_ctzll(live)) : 0x7FFFFFFF;
        uint64_t mb = __ballot(live != 0ull);
        if (mb == 0ull) { exhausted = true; break; }
        cur = __builtin_amdgcn_readlane(local, (int)__builtin_ctzll(mb));
    }

    // ---- phase C (exact fallback): ranks 1024..5999, lazy check ----
    if (nkeep < POST_NMS && exhausted) {
        for (int k = l; k < nkeep; k += 64) {
            float4 bx = *(const float4*)(topb + ((size_t)b*PRE_NMS + keepL[k])*4);
            skx1[k] = bx.x; sky1[k] = bx.y; skx2[k] = bx.z; sky2[k] = bx.w;
            skar[k] = (bx.z - bx.x + 1.0f) * (bx.w - bx.y + 1.0f);
        }
        int base = M;
        while (nkeep < POST_NMS && base < PRE_NMS) {
            int c = base + l;
            float4 bc = make_float4(0.f, 0.f, 0.f, 0.f);
            bool sup = true;
            if (c < PRE_NMS) {
                bc = *(const float4*)(topb + ((size_t)b*PRE_NMS + c)*4);
                sup = false;
            }
            float ac = (bc.z - bc.x + 1.0f) * (bc.w - bc.y + 1.0f);
            for (int k = 0; k < nkeep; ++k) {        // vs kept list (LDS broadcast)
                float xx1 = fmaxf(skx1[k], bc.x);
                float yy1 = fmaxf(sky1[k], bc.y);
                float xx2 = fminf(skx2[k], bc.z);
                float yy2 = fminf(sky2[k], bc.w);
                float iw = fmaxf(0.0f, xx2 - xx1 + 1.0f);
                float ih = fmaxf(0.0f, yy2 - yy1 + 1.0f);
                float inter = iw * ih;
                float iou = inter / ((skar[k] + ac) - inter);
                if (iou > NMS_THRESH) sup = true;
            }
            uint64_t live = __ballot(!sup);
            while (live != 0ull && nkeep < POST_NMS) {
                int j = (int)__builtin_ctzll(live);
                int cj = base + j;
                if (l == 0) keepL[nkeep] = cj;
                float jx1 = __shfl(bc.x, j);
                float jy1 = __shfl(bc.y, j);
                float jx2 = __shfl(bc.z, j);
                float jy2 = __shfl(bc.w, j);
                float ja  = __shfl(ac, j);
                if (l == 0) { skx1[nkeep]=jx1; sky1[nkeep]=jy1; skx2[nkeep]=jx2; sky2[nkeep]=jy2; skar[nkeep]=ja; }
                nkeep++;
                // intra-word suppression by the newly kept box
                float xx1 = fmaxf(jx1, bc.x);
                float yy1 = fmaxf(jy1, bc.y);
                float xx2 = fminf(jx2, bc.z);
                float yy2 = fminf(jy2, bc.w);
                float iw = fmaxf(0.0f, xx2 - xx1 + 1.0f);
                float ih = fmaxf(0.0f, yy2 - yy1 + 1.0f);
                float inter = iw * ih;
                float iou = inter / ((ja + ac) - inter);
                uint64_t kill = __ballot(iou > NMS_THRESH);
                live &= ~kill;
                live &= ~(1ull << j);
            }
            base += 64;
        }
    }
    __syncthreads();

    // ---- output ----
    for (int k = l; k < POST_NMS; k += 64) {
        float* o = out + ((size_t)b*POST_NMS + k)*5;
        o[0] = (float)b;
        if (k < nkeep) {
            float4 bx = *(const float4*)(topb + ((size_t)b*PRE_NMS + keepL[k])*4);
            o[1] = bx.x; o[2] = bx.y; o[3] = bx.z; o[4] = bx.w;
        } else {
            o[1] = 0.0f; o[2] = 0.0f; o[3] = 0.0f; o[4] = 0.0f;
        }
    }
}

extern "C" void kernel_launch(void* const* d_in, const int* in_sizes, int n_in,
                              void* d_out, int out_size, void* d_ws, size_t ws_size,
                              hipStream_t stream) {
    const float* scores   = (const float*)d_in[0];
    const float* deltas   = (const float*)d_in[1];
    const float* img_info = (const float*)d_in[2];
    const float* anchors  = (const float*)d_in[3];
    float* out = (float*)d_out;

    uint8_t* ws = (uint8_t*)d_ws;
    float*    topb = (float*)ws;                    //   384,000 B (+pad)
    uint64_t* msk  = (uint64_t*)(ws + 393216);      //   524,288 B (4 * 1024 * 16 * 8)

    select_sort<<<NB, 1024, 0, stream>>>(scores, deltas, img_info, anchors, topb);

    dim3 mg(MW, MW, NB);
    nms_mask_small<<<mg, 64, 0, stream>>>(topb, msk);

    nms_scan_lds<<<NB, 64, 0, stream>>>(msk, topb, out);
}

// Round 7
// 202.369 us; speedup vs baseline: 2.9184x; 1.1991x over previous
//
#include <hip/hip_runtime.h>
#include <stdint.h>

#define HH 64
#define WW 64
#define AA 9
#define N_PER (HH*WW*AA)   // 36864
#define NB 4
#define PRE_NMS 6000
#define POST_NMS 300
#define NMS_THRESH 0.7f
#define FEAT_STRIDE 16
#define M 1024             // in-LDS NMS candidate window
#define MW 16              // u64 words per mask row (1024/64)
#define BINS 8192          // 13-bit radix bins (top bits of monotonic key)
#define SCAT_MAX 8000      // scatter area capacity (expected ~6560 max)

// =====================================================================
// Kernel 1: exact top-6000 select + rank by counting argument.
// One WG of 1024 threads per image.
//   key = (monotonic(score) << 32) | ~index   (unique, descending order
//   == jax.lax.top_k order with lowest-index tie-break)
//   rank(k) = #{keys > k} = suffix_count(bin(k)) + #{greater in bin}.
// No sort, no gather: each selected key decodes its box and writes
// topb[rank] directly.
// =====================================================================
__global__ void __launch_bounds__(1024) select_rank(const float* __restrict__ scores,
                                                    const float* __restrict__ deltas,
                                                    const float* __restrict__ img_info,
                                                    const float* __restrict__ anchors,
                                                    float* __restrict__ topb) // NB*PRE_NMS*4
{
#pragma clang fp contract(off)
    int b = blockIdx.x;
    int t = threadIdx.x;
    __shared__ uint32_t H[BINS];        // 32 KB histogram (preserved)
    __shared__ uint32_t SS[BINS];       // 32 KB excl-suffix sums -> cursors -> bin ends
    __shared__ uint64_t scat[SCAT_MAX]; // 64 KB bin-partitioned keys
    __shared__ uint32_t blksum[1024];   // scan scratch
    __shared__ int shB1;
    __shared__ uint32_t shNscat;

    auto keyof = [&](int j) -> uint64_t {
        int a = j >> 12, hw = j & 4095;
        float sc = scores[((size_t)b*18 + 9 + a)*4096 + hw];
        uint32_t u = __float_as_uint(sc);
        u = (u & 0x80000000u) ? ~u : (u | 0x80000000u);
        uint32_t i = (uint32_t)(hw*9 + a);            // reference flat index
        return ((uint64_t)u << 32) | (uint32_t)(~i);
    };

    // ---------- phase 1: 13-bit histogram ----------
    for (int i = t; i < BINS; i += 1024) H[i] = 0u;
    __syncthreads();
    for (int j = t; j < N_PER; j += 1024)
        atomicAdd(&H[(uint32_t)(keyof(j) >> 51)], 1u);
    __syncthreads();

    // ---------- phase 2: exclusive suffix scan  SS[b] = sum_{b'>b} H[b'] ----------
    int base = t * 8;
    uint32_t loc[8];
    uint32_t lsum = 0;
    #pragma unroll
    for (int k = 0; k < 8; ++k) { loc[k] = H[base + k]; lsum += loc[k]; }
    blksum[t] = lsum;
    __syncthreads();
    for (int off = 1; off < 1024; off <<= 1) {        // Hillis-Steele inclusive suffix
        uint32_t add = (t + off < 1024) ? blksum[t + off] : 0u;
        __syncthreads();
        blksum[t] += add;
        __syncthreads();
    }
    uint32_t run = (t < 1023) ? blksum[t + 1] : 0u;   // exclusive over blocks
    #pragma unroll
    for (int k = 7; k >= 0; --k) { SS[base + k] = run; run += loc[k]; }
    __syncthreads();

    // ---------- phase 3: find cutoff bin B1 (rank 6000 falls inside) ----------
    for (int i = t; i < BINS; i += 1024) {
        if (SS[i] < PRE_NMS && SS[i] + H[i] >= PRE_NMS) shB1 = i;
    }
    __syncthreads();
    int B1 = shB1;
    if (t == 0) shNscat = SS[B1] + H[B1];             // read BEFORE cursor mutation
    __syncthreads();

    // ---------- phase 4: scatter all keys of bins >= B1 (cursors = SS) ----------
    for (int j = t; j < N_PER; j += 1024) {
        uint64_t k64 = keyof(j);
        uint32_t bin = (uint32_t)(k64 >> 51);
        if ((int)bin >= B1) {
            uint32_t slot = atomicAdd(&SS[bin], 1u);
            if (slot < SCAT_MAX) scat[slot] = k64;
        }
    }
    __syncthreads();
    uint32_t Nscat = min(shNscat, (uint32_t)SCAT_MAX);

    // ---------- phase 5: rank within bin, decode, write topb[rank] ----------
    float maxx = img_info[1] - 1.0f;
    float maxy = img_info[0] - 1.0f;
    for (uint32_t s = t; s < Nscat; s += 1024) {
        uint64_t k64 = scat[s];
        uint32_t bin = (uint32_t)(k64 >> 51);
        uint32_t end = SS[bin];                       // after scatter: bin end
        uint32_t start = end - H[bin];
        uint32_t cnt = 0;
        for (uint32_t j = start; j < end; ++j)
            cnt += (scat[j] > k64) ? 1u : 0u;         // broadcast-friendly LDS reads
        uint32_t r = start + cnt;                     // exact global descending rank
        if (r < PRE_NMS) {
            uint32_t i = ~(uint32_t)(k64 & 0xFFFFFFFFu);
            int a = (int)(i % 9u);
            int hw = (int)(i / 9u);
            int h = hw >> 6, w = hw & 63;
            float sx = (float)(w * FEAT_STRIDE);
            float sy = (float)(h * FEAT_STRIDE);
            float ax1 = anchors[a*4+0] + sx;
            float ay1 = anchors[a*4+1] + sy;
            float ax2 = anchors[a*4+2] + sx;
            float ay2 = anchors[a*4+3] + sy;
            float width  = ax2 - ax1 + 1.0f;
            float height = ay2 - ay1 + 1.0f;
            float cx = ax1 + 0.5f * width;
            float cy = ay1 + 0.5f * height;
            size_t dbase = ((size_t)b*36 + a*4) * 4096 + hw;
            float dx = deltas[dbase];
            float dy = deltas[dbase + 4096];
            float dw = deltas[dbase + 2*4096];
            float dh = deltas[dbase + 3*4096];
            float pcx = dx * width + cx;
            float pcy = dy * height + cy;
            float pw = (float)exp((double)dw) * width;   // correctly-rounded f32 exp
            float ph = (float)exp((double)dh) * height;
            float x1 = pcx - 0.5f * pw;
            float y1 = pcy - 0.5f * ph;
            float x2 = pcx + 0.5f * pw;
            float y2 = pcy + 0.5f * ph;
            x1 = fminf(fmaxf(x1, 0.0f), maxx);
            y1 = fminf(fmaxf(y1, 0.0f), maxy);
            x2 = fminf(fmaxf(x2, 0.0f), maxx);
            y2 = fminf(fmaxf(y2, 0.0f), maxy);
            *(float4*)(topb + ((size_t)b*PRE_NMS + r)*4) = make_float4(x1, y1, x2, y2);
        }
    }
}

// =====================================================================
// Kernel 2: suppression bitmask for the TOP-1024 window only.
// (unchanged from round 6)
// =====================================================================
__global__ void __launch_bounds__(64) nms_mask_small(const float* __restrict__ topb,
                                                     uint64_t* __restrict__ msk) {
#pragma clang fp contract(off)
    int jblock = blockIdx.x;  // 0..15
    int iblock = blockIdx.y;  // 0..15
    int b = blockIdx.z;
    int t = threadIdx.x;      // 0..63
    __shared__ float4 jb[64];
    __shared__ float jarea[64];
    int j0 = jblock*64;
    {
        float4 bj = *(const float4*)(topb + ((size_t)b*PRE_NMS + j0 + t)*4);
        jb[t] = bj;
        jarea[t] = (bj.z - bj.x + 1.0f) * (bj.w - bj.y + 1.0f);
    }
    __syncthreads();
    int i = iblock*64 + t;
    float4 bi = *(const float4*)(topb + ((size_t)b*PRE_NMS + i)*4);
    float areai = (bi.z - bi.x + 1.0f) * (bi.w - bi.y + 1.0f);
    uint64_t bits = 0;
    for (int jj = 0; jj < 64; ++jj) {
        float4 bj = jb[jj];
        float xx1 = fmaxf(bi.x, bj.x);
        float yy1 = fmaxf(bi.y, bj.y);
        float xx2 = fminf(bi.z, bj.z);
        float yy2 = fminf(bi.w, bj.w);
        float iw = fmaxf(0.0f, xx2 - xx1 + 1.0f);
        float ih = fmaxf(0.0f, yy2 - yy1 + 1.0f);
        float inter = iw * ih;
        float iou = inter / ((areai + jarea[jj]) - inter);
        if (iou > NMS_THRESH) bits |= (1ull << jj);
    }
    msk[((size_t)b*M + i)*MW + jblock] = bits;
}

// =====================================================================
// Kernel 3: single-wave greedy scan, mask fully in LDS.
// (unchanged from round 6)
// =====================================================================
__global__ void __launch_bounds__(64) nms_scan_lds(const uint64_t* __restrict__ msk,
                                                   const float* __restrict__ topb,
                                                   float* __restrict__ out) {
#pragma clang fp contract(off)
    int b = blockIdx.x;
    int l = threadIdx.x;
    __shared__ __align__(16) uint64_t rows[M][MW];   // 131,072 B
    __shared__ int keepL[POST_NMS];
    __shared__ float skx1[POST_NMS], sky1[POST_NMS], skx2[POST_NMS], sky2[POST_NMS], skar[POST_NMS];

    // ---- stage the 128 KB mask into LDS (linear, wave-uniform dest) ----
    const uint8_t* src0 = (const uint8_t*)(msk + (size_t)b*M*MW);
    uint8_t* dst0 = (uint8_t*)&rows[0][0];
    for (int it = 0; it < (M*MW*8)/1024; ++it) {     // 128 issues of 1 KB
        __builtin_amdgcn_global_load_lds(
            (const __attribute__((address_space(1))) uint32_t*)(src0 + it*1024 + l*16),
            (__attribute__((address_space(3))) uint32_t*)(dst0 + it*1024 + l*16),
            16, 0, 0);
    }
    asm volatile("s_waitcnt vmcnt(0)" ::: "memory");
    __builtin_amdgcn_sched_barrier(0);

    // ---- phase A: in-LDS bit walk over ranks 0..1023 ----
    uint64_t remv = 0ull;      // lane l<16 owns bits [64l, 64l+64)
    int nkeep = 0;
    int cur = 0;               // rank 0 always kept first
    bool exhausted = false;
    while (true) {
        if (l == 0) keepL[nkeep] = cur;
        nkeep++;
        if (nkeep >= POST_NMS) break;
        uint64_t rw = (l < MW) ? rows[cur][l] : 0ull;
        remv |= rw;            // row includes self-bit (IoU=1)
        uint64_t live = (l < MW) ? ~remv : 0ull;
        int local = live ? (l*64 + (int)__builtin_ctzll(live)) : 0x7FFFFFFF;
        uint64_t mb = __ballot(live != 0ull);
        if (mb == 0ull) { exhausted = true; break; }
        cur = __builtin_amdgcn_readlane(local, (int)__builtin_ctzll(mb));
    }

    // ---- phase C (exact fallback): ranks 1024..5999, lazy check ----
    if (nkeep < POST_NMS && exhausted) {
        for (int k = l; k < nkeep; k += 64) {
            float4 bx = *(const float4*)(topb + ((size_t)b*PRE_NMS + keepL[k])*4);
            skx1[k] = bx.x; sky1[k] = bx.y; skx2[k] = bx.z; sky2[k] = bx.w;
            skar[k] = (bx.z - bx.x + 1.0f) * (bx.w - bx.y + 1.0f);
        }
        int base = M;
        while (nkeep < POST_NMS && base < PRE_NMS) {
            int c = base + l;
            float4 bc = make_float4(0.f, 0.f, 0.f, 0.f);
            bool sup = true;
            if (c < PRE_NMS) {
                bc = *(const float4*)(topb + ((size_t)b*PRE_NMS + c)*4);
                sup = false;
            }
            float ac = (bc.z - bc.x + 1.0f) * (bc.w - bc.y + 1.0f);
            for (int k = 0; k < nkeep; ++k) {        // vs kept list (LDS broadcast)
                float xx1 = fmaxf(skx1[k], bc.x);
                float yy1 = fmaxf(sky1[k], bc.y);
                float xx2 = fminf(skx2[k], bc.z);
                float yy2 = fminf(sky2[k], bc.w);
                float iw = fmaxf(0.0f, xx2 - xx1 + 1.0f);
                float ih = fmaxf(0.0f, yy2 - yy1 + 1.0f);
                float inter = iw * ih;
                float iou = inter / ((skar[k] + ac) - inter);
                if (iou > NMS_THRESH) sup = true;
            }
            uint64_t live = __ballot(!sup);
            while (live != 0ull && nkeep < POST_NMS) {
                int j = (int)__builtin_ctzll(live);
                int cj = base + j;
                if (l == 0) keepL[nkeep] = cj;
                float jx1 = __shfl(bc.x, j);
                float jy1 = __shfl(bc.y, j);
                float jx2 = __shfl(bc.z, j);
                float jy2 = __shfl(bc.w, j);
                float ja  = __shfl(ac, j);
                if (l == 0) { skx1[nkeep]=jx1; sky1[nkeep]=jy1; skx2[nkeep]=jx2; sky2[nkeep]=jy2; skar[nkeep]=ja; }
                nkeep++;
                float xx1 = fmaxf(jx1, bc.x);
                float yy1 = fmaxf(jy1, bc.y);
                float xx2 = fminf(jx2, bc.z);
                float yy2 = fminf(jy2, bc.w);
                float iw = fmaxf(0.0f, xx2 - xx1 + 1.0f);
                float ih = fmaxf(0.0f, yy2 - yy1 + 1.0f);
                float inter = iw * ih;
                float iou = inter / ((ja + ac) - inter);
                uint64_t kill = __ballot(iou > NMS_THRESH);
                live &= ~kill;
                live &= ~(1ull << j);
            }
            base += 64;
        }
    }
    __syncthreads();

    // ---- output ----
    for (int k = l; k < POST_NMS; k += 64) {
        float* o = out + ((size_t)b*POST_NMS + k)*5;
        o[0] = (float)b;
        if (k < nkeep) {
            float4 bx = *(const float4*)(topb + ((size_t)b*PRE_NMS + keepL[k])*4);
            o[1] = bx.x; o[2] = bx.y; o[3] = bx.z; o[4] = bx.w;
        } else {
            o[1] = 0.0f; o[2] = 0.0f; o[3] = 0.0f; o[4] = 0.0f;
        }
    }
}

extern "C" void kernel_launch(void* const* d_in, const int* in_sizes, int n_in,
                              void* d_out, int out_size, void* d_ws, size_t ws_size,
                              hipStream_t stream) {
    const float* scores   = (const float*)d_in[0];
    const float* deltas   = (const float*)d_in[1];
    const float* img_info = (const float*)d_in[2];
    const float* anchors  = (const float*)d_in[3];
    float* out = (float*)d_out;

    uint8_t* ws = (uint8_t*)d_ws;
    float*    topb = (float*)ws;                    //   384,000 B (+pad)
    uint64_t* msk  = (uint64_t*)(ws + 393216);      //   524,288 B (4 * 1024 * 16 * 8)

    select_rank<<<NB, 1024, 0, stream>>>(scores, deltas, img_info, anchors, topb);

    dim3 mg(MW, MW, NB);
    nms_mask_small<<<mg, 64, 0, stream>>>(topb, msk);

    nms_scan_lds<<<NB, 64, 0, stream>>>(msk, topb, out);
}